// Round 2
// baseline (81.233 us; speedup 1.0000x reference)
//
#include <hip/hip_runtime.h>
#include <hip/hip_bf16.h>

#define NF 262144   // C*H*W
#define NROWS 32    // batch
#define SLICE 1120  // floats per accumulator slice: 1024 cross + 32 pos + 32 sq1 + 32 sq2

typedef __attribute__((ext_vector_type(8))) __bf16 bf16x8;
typedef __attribute__((ext_vector_type(16))) float f32x16;

__device__ __forceinline__ float sigmoid_fast(float x) {
    float e = __expf(-x);
    return __builtin_amdgcn_rcpf(1.0f + e);
}

// slice layout (floats): [0,1024) cross[32][32]; [1024,1056) pos; [1056,1088) sq1; [1088,1120) sq2
__global__ __launch_bounds__(256) void cl_main(const float* __restrict__ in1,
                                               const float* __restrict__ in2,
                                               const float* __restrict__ msk,
                                               float* __restrict__ ws,
                                               int kmask) {
    const int tid  = threadIdx.x;
    const int wid  = tid >> 6;
    const int lane = tid & 63;
    const int r    = lane & 31;   // batch row this lane owns (MFMA A/B frag row)
    const int g    = lane >> 5;   // k-group (0/1) within 16-col MFMA step
    const int gw   = blockIdx.x * 4 + wid;           // global wave id, [0,8192)
    const size_t rowoff = (size_t)r * NF;
    const int cbase = gw * 32 + g * 8;               // this wave spans 32 cols

    f32x16 acc;
    #pragma unroll
    for (int k = 0; k < 16; ++k) acc[k] = 0.0f;
    float pos = 0.0f, q1 = 0.0f, q2 = 0.0f;

    #pragma unroll
    for (int s = 0; s < 2; ++s) {
        const int c0 = cbase + s * 16;
        float xa[8], xb[8], xm[8];
        const float4* p1 = reinterpret_cast<const float4*>(in1 + rowoff + c0);
        const float4* p2 = reinterpret_cast<const float4*>(in2 + rowoff + c0);
        const float4* pm = reinterpret_cast<const float4*>(msk + rowoff + c0);
        *reinterpret_cast<float4*>(&xa[0]) = p1[0];
        *reinterpret_cast<float4*>(&xa[4]) = p1[1];
        *reinterpret_cast<float4*>(&xb[0]) = p2[0];
        *reinterpret_cast<float4*>(&xb[4]) = p2[1];
        *reinterpret_cast<float4*>(&xm[0]) = pm[0];
        *reinterpret_cast<float4*>(&xm[4]) = pm[1];

        bf16x8 fa, fb;
        #pragma unroll
        for (int e = 0; e < 8; ++e) {
            float sa = sigmoid_fast(xa[e]);
            float sb = sigmoid_fast(xb[e]);
            float t = xm[e] * (sa - sb);
            pos = fmaf(t, t, pos);
            q1  = fmaf(sa, sa, q1);
            q2  = fmaf(sb, sb, q2);
            fa[e] = (__bf16)sa;
            fb[e] = (__bf16)sb;
        }
        // cross[i][j] += sum_k x1[i][k] * x2[j][k]
        acc = __builtin_amdgcn_mfma_f32_32x32x16_bf16(fa, fb, acc, 0, 0, 0);
    }

    // ---- block reduction in LDS ----
    __shared__ float s_cross[32][32];
    __shared__ float s_vec[3][32];
    for (int idx = tid; idx < 1024; idx += 256) (&s_cross[0][0])[idx] = 0.0f;
    if (tid < 96) (&s_vec[0][0])[tid] = 0.0f;
    __syncthreads();

    pos += __shfl_down(pos, 32);
    q1  += __shfl_down(q1, 32);
    q2  += __shfl_down(q2, 32);
    if (lane < 32) {
        atomicAdd(&s_vec[0][r], pos);
        atomicAdd(&s_vec[1][r], q1);
        atomicAdd(&s_vec[2][r], q2);
    }
    const int col = lane & 31;
    const int rhi = (lane >> 5) * 4;
    #pragma unroll
    for (int reg = 0; reg < 16; ++reg) {
        const int row = (reg & 3) + 8 * (reg >> 2) + rhi;  // verified C/D mapping
        atomicAdd(&s_cross[row][col], acc[reg]);
    }
    __syncthreads();

    // ---- sharded global accumulation (slice = blockIdx & kmask) ----
    float* slice = ws + (size_t)(blockIdx.x & kmask) * SLICE;
    for (int idx = tid; idx < 1024; idx += 256) atomicAdd(&slice[idx], (&s_cross[0][0])[idx]);
    if (tid < 96) atomicAdd(&slice[1024 + tid], (&s_vec[0][0])[tid]);
}

__global__ __launch_bounds__(1024) void cl_final(const float* __restrict__ ws,
                                                 float* __restrict__ out,
                                                 int nslices) {
    __shared__ float s_loss[32];
    const int tid = threadIdx.x;
    const int i = tid >> 5, j = tid & 31;
    const float invN = 1.0f / (float)NF;

    float c = 0.0f, p = 0.0f, s1 = 0.0f, s2 = 0.0f;
    for (int k = 0; k < nslices; ++k) {
        const float* sl = ws + (size_t)k * SLICE;
        c  += sl[i * 32 + j];
        p  += sl[1024 + i];
        s1 += sl[1056 + i];
        s2 += sl[1088 + j];
    }

    float d = (s1 + s2 - 2.0f * c) * invN;
    float sim = (i == j) ? 0.0f : expf(-d * 10.0f);   // TAU = 0.1
    #pragma unroll
    for (int off = 16; off; off >>= 1) sim += __shfl_xor(sim, off);

    if (j == 0) {
        float sp = expf(-p * invN * 10.0f);
        s_loss[i] = -logf(sp / (sp + sim));
    }
    __syncthreads();
    if (tid == 0) {
        float t = 0.0f;
        #pragma unroll
        for (int k = 0; k < 32; ++k) t += s_loss[k];
        out[0] = t * (1.0f / 32.0f);
    }
}

extern "C" void kernel_launch(void* const* d_in, const int* in_sizes, int n_in,
                              void* d_out, int out_size, void* d_ws, size_t ws_size,
                              hipStream_t stream) {
    const float* in1 = (const float*)d_in[0];
    const float* in2 = (const float*)d_in[1];
    const float* msk = (const float*)d_in[2];
    float* out = (float*)d_out;
    float* ws  = (float*)d_ws;

    // number of accumulator slices: largest power of two <= min(64, capacity)
    int kcap = (int)(ws_size / (SLICE * sizeof(float)));
    int K = 1;
    while (K * 2 <= kcap && K < 64) K *= 2;

    hipMemsetAsync(ws, 0, (size_t)K * SLICE * sizeof(float), stream);
    cl_main<<<2048, 256, 0, stream>>>(in1, in2, msk, ws, K - 1);
    cl_final<<<1, 1024, 0, stream>>>(ws, out, K);
}

// Round 3
// 58.484 us; speedup vs baseline: 1.3890x; 1.3890x over previous
//
#include <hip/hip_runtime.h>
#include <hip/hip_bf16.h>

#define NF 262144   // C*H*W
#define NROWS 32    // batch
#define SLICE 1120  // floats per slice: 1024 cross + 32 pos + 32 sq1 + 32 sq2
#define NSLICES 16

typedef __attribute__((ext_vector_type(8))) __bf16 bf16x8;
typedef __attribute__((ext_vector_type(16))) float f32x16;

__device__ __forceinline__ float sigmoid_fast(float x) {
    float e = __expf(-x);
    return __builtin_amdgcn_rcpf(1.0f + e);
}

__device__ __forceinline__ void load_step(const float* __restrict__ p1,
                                          const float* __restrict__ p2,
                                          const float* __restrict__ pm,
                                          int off, float4* A, float4* B, float4* M) {
    const float4* q1 = reinterpret_cast<const float4*>(p1 + off);
    const float4* q2 = reinterpret_cast<const float4*>(p2 + off);
    const float4* qm = reinterpret_cast<const float4*>(pm + off);
    A[0] = q1[0]; A[1] = q1[1];
    B[0] = q2[0]; B[1] = q2[1];
    M[0] = qm[0]; M[1] = qm[1];
}

__device__ __forceinline__ void compute_step(const float4* A, const float4* B, const float4* M,
                                             f32x16& acc, float& pos, float& q1, float& q2) {
    const float* xa = reinterpret_cast<const float*>(A);
    const float* xb = reinterpret_cast<const float*>(B);
    const float* xm = reinterpret_cast<const float*>(M);
    bf16x8 fa, fb;
    #pragma unroll
    for (int e = 0; e < 8; ++e) {
        float sa = sigmoid_fast(xa[e]);
        float sb = sigmoid_fast(xb[e]);
        float t = xm[e] * (sa - sb);
        pos = fmaf(t, t, pos);
        q1  = fmaf(sa, sa, q1);
        q2  = fmaf(sb, sb, q2);
        fa[e] = (__bf16)sa;
        fb[e] = (__bf16)sb;
    }
    acc = __builtin_amdgcn_mfma_f32_32x32x16_bf16(fa, fb, acc, 0, 0, 0);
}

// slice layout (floats): [0,1024) cross[32][32]; [1024,1056) pos; [1056,1088) sq1; [1088,1120) sq2
__global__ __launch_bounds__(256, 4) void cl_main(const float* __restrict__ in1,
                                                  const float* __restrict__ in2,
                                                  const float* __restrict__ msk,
                                                  float* __restrict__ ws) {
    const int tid  = threadIdx.x;
    const int wid  = tid >> 6;
    const int lane = tid & 63;
    const int r    = lane & 31;   // batch row this lane owns (MFMA A/B frag row)
    const int g    = lane >> 5;   // k-group (0/1) within 16-col MFMA step
    const int gw   = blockIdx.x * 4 + wid;           // global wave id, [0,4096)
    const size_t rowoff = (size_t)r * NF;
    const int cbase = gw * 64 + g * 8;               // wave spans 64 cols (4 MFMA steps)

    const float* p1 = in1 + rowoff + cbase;
    const float* p2 = in2 + rowoff + cbase;
    const float* pm = msk + rowoff + cbase;

    f32x16 acc;
    #pragma unroll
    for (int k = 0; k < 16; ++k) acc[k] = 0.0f;
    float pos = 0.0f, q1 = 0.0f, q2 = 0.0f;

    // 2-deep software pipeline over 4 steps: ~12 loads in flight per wave
    float4 A0[2], B0[2], M0[2], A1[2], B1[2], M1[2];
    load_step(p1, p2, pm,  0, A0, B0, M0);
    load_step(p1, p2, pm, 16, A1, B1, M1);
    compute_step(A0, B0, M0, acc, pos, q1, q2);
    load_step(p1, p2, pm, 32, A0, B0, M0);
    compute_step(A1, B1, M1, acc, pos, q1, q2);
    load_step(p1, p2, pm, 48, A1, B1, M1);
    compute_step(A0, B0, M0, acc, pos, q1, q2);
    compute_step(A1, B1, M1, acc, pos, q1, q2);

    // ---- block reduction in LDS ----
    __shared__ float s_cross[32][32];
    __shared__ float s_vec[3][32];
    for (int idx = tid; idx < 1024; idx += 256) (&s_cross[0][0])[idx] = 0.0f;
    if (tid < 96) (&s_vec[0][0])[tid] = 0.0f;
    __syncthreads();

    pos += __shfl_down(pos, 32);
    q1  += __shfl_down(q1, 32);
    q2  += __shfl_down(q2, 32);
    if (lane < 32) {
        atomicAdd(&s_vec[0][r], pos);
        atomicAdd(&s_vec[1][r], q1);
        atomicAdd(&s_vec[2][r], q2);
    }
    const int col = lane & 31;
    const int rhi = (lane >> 5) * 4;
    #pragma unroll
    for (int reg = 0; reg < 16; ++reg) {
        const int row = (reg & 3) + 8 * (reg >> 2) + rhi;  // verified C/D mapping
        atomicAdd(&s_cross[row][col], acc[reg]);
    }
    __syncthreads();

    // ---- sharded global accumulation ----
    float* slice = ws + (size_t)(blockIdx.x & (NSLICES - 1)) * SLICE;
    for (int idx = tid; idx < 1024; idx += 256) atomicAdd(&slice[idx], (&s_cross[0][0])[idx]);
    if (tid < 96) atomicAdd(&slice[1024 + tid], (&s_vec[0][0])[tid]);
}

__global__ __launch_bounds__(1024) void cl_final(const float* __restrict__ ws,
                                                 float* __restrict__ out) {
    __shared__ float s_loss[32];
    const int tid = threadIdx.x;
    const int i = tid >> 5, j = tid & 31;
    const float invN = 1.0f / (float)NF;

    float c = 0.0f, p = 0.0f, s1 = 0.0f, s2 = 0.0f;
    #pragma unroll
    for (int k = 0; k < NSLICES; ++k) {   // 16 independent loads per term
        const float* sl = ws + (size_t)k * SLICE;
        c  += sl[i * 32 + j];
        p  += sl[1024 + i];
        s1 += sl[1056 + i];
        s2 += sl[1088 + j];
    }

    float d = (s1 + s2 - 2.0f * c) * invN;
    float sim = (i == j) ? 0.0f : expf(-d * 10.0f);   // TAU = 0.1
    #pragma unroll
    for (int off = 16; off; off >>= 1) sim += __shfl_xor(sim, off);

    if (j == 0) {
        float sp = expf(-p * invN * 10.0f);
        s_loss[i] = -logf(sp / (sp + sim));
    }
    __syncthreads();
    if (tid == 0) {
        float t = 0.0f;
        #pragma unroll
        for (int k = 0; k < 32; ++k) t += s_loss[k];
        out[0] = t * (1.0f / 32.0f);
    }
}

extern "C" void kernel_launch(void* const* d_in, const int* in_sizes, int n_in,
                              void* d_out, int out_size, void* d_ws, size_t ws_size,
                              hipStream_t stream) {
    const float* in1 = (const float*)d_in[0];
    const float* in2 = (const float*)d_in[1];
    const float* msk = (const float*)d_in[2];
    float* out = (float*)d_out;
    float* ws  = (float*)d_ws;

    hipMemsetAsync(ws, 0, NSLICES * SLICE * sizeof(float), stream);
    cl_main<<<1024, 256, 0, stream>>>(in1, in2, msk, ws);
    cl_final<<<1, 1024, 0, stream>>>(ws, out);
}